// Round 1
// baseline (3529.606 us; speedup 1.0000x reference)
//
#include <hip/hip_runtime.h>

#define N_NODES 50000
#define N_EDGES 800000
#define D 256
#define BM 32
#define BK 32

// ---------------------------------------------------------------------------
// Kernel 1: edge-parallel scatter-add aggregation.
//   agg[r, :] += vals[e] * x[c, :]   for each edge e=(r,c)
// One wave (64 lanes) per edge; lane i handles float4 channel chunk i.
// 64 lanes * 4 floats = 256 = D exactly.
// ---------------------------------------------------------------------------
__global__ __launch_bounds__(256) void spmm_atomic(
    const float* __restrict__ x,
    const int* __restrict__ erow,
    const int* __restrict__ ecol,
    const float* __restrict__ evals,
    float* __restrict__ agg)
{
    long long gid = (long long)blockIdx.x * blockDim.x + threadIdx.x;
    int e    = (int)(gid >> 6);
    int lane = (int)(gid & 63);
    if (e >= N_EDGES) return;

    int   r = erow[e];
    int   c = ecol[e];
    float v = evals[e];

    float4 a = ((const float4*)(x + (size_t)c * D))[lane];
    float* dst = agg + (size_t)r * D + lane * 4;
    atomicAdd(dst + 0, v * a.x);
    atomicAdd(dst + 1, v * a.y);
    atomicAdd(dst + 2, v * a.z);
    atomicAdd(dst + 3, v * a.w);
}

// ---------------------------------------------------------------------------
// Kernel 2: out = relu(agg @ W + bias), fp32 vector GEMM.
// Block = 256 threads (one per output column), tile = BM rows.
// A-tile staged in LDS transposed (lds[kk][r]) with +1 pad so the
// cooperative write is conflict-free; reads are same-address broadcasts
// (free). W streamed from global: consecutive lanes -> consecutive cols,
// coalesced, and W (256 KB) lives in L1/L2 across blocks.
// ---------------------------------------------------------------------------
__global__ __launch_bounds__(256) void gemm_bias_relu(
    const float* __restrict__ agg,
    const float* __restrict__ W,
    const float* __restrict__ bias,
    float* __restrict__ out)
{
    __shared__ float lds[BK][BM + 1];   // +1 pad: cooperative write is conflict-free

    int col = threadIdx.x;              // 0..255
    int m0  = blockIdx.x * BM;

    float acc[BM];
#pragma unroll
    for (int i = 0; i < BM; ++i) acc[i] = 0.f;

    for (int k0 = 0; k0 < D; k0 += BK) {
        // cooperative load of BM x BK A-tile (1024 floats, 4 per thread)
        int t = threadIdx.x;
#pragma unroll
        for (int i = 0; i < (BM * BK) / 256; ++i) {
            int idx = t + i * 256;
            int r   = idx >> 5;          // idx / BK
            int kk  = idx & (BK - 1);
            int m   = m0 + r;
            float val = (m < N_NODES) ? agg[(size_t)m * D + k0 + kk] : 0.f;
            lds[kk][r] = val;
        }
        __syncthreads();

#pragma unroll
        for (int kk = 0; kk < BK; ++kk) {
            float w = W[(size_t)(k0 + kk) * D + col];
#pragma unroll
            for (int r = 0; r < BM; ++r)
                acc[r] += lds[kk][r] * w;
        }
        __syncthreads();
    }

    float b = bias[col];
#pragma unroll
    for (int r = 0; r < BM; ++r) {
        int m = m0 + r;
        if (m < N_NODES) {
            float o = acc[r] + b;
            out[(size_t)m * D + col] = o > 0.f ? o : 0.f;
        }
    }
}

extern "C" void kernel_launch(void* const* d_in, const int* in_sizes, int n_in,
                              void* d_out, int out_size, void* d_ws, size_t ws_size,
                              hipStream_t stream) {
    const float* x     = (const float*)d_in[0];
    const int*   erow  = (const int*)d_in[1];
    const int*   ecol  = (const int*)d_in[2];
    const float* evals = (const float*)d_in[3];
    const float* W     = (const float*)d_in[4];
    const float* bias  = (const float*)d_in[5];
    float*       out   = (float*)d_out;
    float*       agg   = (float*)d_ws;   // 50000*256*4 = 51.2 MB scratch

    size_t agg_bytes = (size_t)N_NODES * D * sizeof(float);
    hipMemsetAsync(agg, 0, agg_bytes, stream);

    // SpMM: one wave per edge -> E*64 threads
    long long total_threads = (long long)N_EDGES * 64;
    int threads = 256;
    int blocks_spmm = (int)((total_threads + threads - 1) / threads);  // 200000
    spmm_atomic<<<blocks_spmm, threads, 0, stream>>>(x, erow, ecol, evals, agg);

    // GEMM + bias + relu
    int blocks_gemm = (N_NODES + BM - 1) / BM;                         // 1563
    gemm_bias_relu<<<blocks_gemm, 256, 0, stream>>>(agg, W, bias, out);
}

// Round 2
// 512.620 us; speedup vs baseline: 6.8854x; 6.8854x over previous
//
#include <hip/hip_runtime.h>

#define N_NODES 50000
#define N_EDGES 800000
#define D 256

// ---------------------------------------------------------------------------
// Workspace layout (all 16B-aligned regions):
//   agg       : N_NODES * D floats   (51.2 MB)
//   cnt       : N_NODES ints
//   row_start : N_NODES+1 ints
//   cursor    : N_NODES ints
//   scol      : N_EDGES ints
//   sval      : N_EDGES floats
// total ~58.4 MB
// ---------------------------------------------------------------------------

// --- CSR build step 1: histogram of row degrees --------------------------
__global__ __launch_bounds__(256) void hist_kernel(const int* __restrict__ erow,
                                                   int* __restrict__ cnt) {
    int e = blockIdx.x * 256 + threadIdx.x;
    if (e < N_EDGES) atomicAdd(&cnt[erow[e]], 1);
}

// --- CSR build step 2: exclusive prefix sum (single block) ---------------
__global__ __launch_bounds__(1024) void scan_kernel(const int* __restrict__ cnt,
                                                    int* __restrict__ row_start,
                                                    int* __restrict__ cursor) {
    __shared__ int s[1024];
    const int CHUNK = (N_NODES + 1023) / 1024;   // 49
    int t = threadIdx.x;
    int base = t * CHUNK;
    int sum = 0;
    for (int i = 0; i < CHUNK; ++i) {
        int idx = base + i;
        if (idx < N_NODES) sum += cnt[idx];
    }
    s[t] = sum;
    __syncthreads();
    // Hillis-Steele inclusive scan over 1024 partials
    for (int off = 1; off < 1024; off <<= 1) {
        int v = (t >= off) ? s[t - off] : 0;
        __syncthreads();
        s[t] += v;
        __syncthreads();
    }
    int excl = s[t] - sum;    // exclusive prefix for this chunk
    for (int i = 0; i < CHUNK; ++i) {
        int idx = base + i;
        if (idx < N_NODES) {
            row_start[idx] = excl;
            cursor[idx]    = excl;
            excl += cnt[idx];
        }
    }
    if (t == 0) row_start[N_NODES] = N_EDGES;
}

// --- CSR build step 3: scatter edges into row-sorted order ---------------
__global__ __launch_bounds__(256) void scatter_kernel(const int* __restrict__ erow,
                                                      const int* __restrict__ ecol,
                                                      const float* __restrict__ evals,
                                                      int* __restrict__ cursor,
                                                      int* __restrict__ scol,
                                                      float* __restrict__ sval) {
    int e = blockIdx.x * 256 + threadIdx.x;
    if (e >= N_EDGES) return;
    int r = erow[e];
    int pos = atomicAdd(&cursor[r], 1);
    scol[pos] = ecol[e];
    sval[pos] = evals[e];
}

// --- Aggregation: one wave per row, no atomics ---------------------------
// lane i holds float4 channel chunk i (64*4 = 256 = D). Edge list is
// wave-uniform -> scalar loads; x gather is 1KB coalesced per edge.
__global__ __launch_bounds__(256) void aggregate_kernel(const float* __restrict__ x,
                                                        const int* __restrict__ row_start,
                                                        const int* __restrict__ scol,
                                                        const float* __restrict__ sval,
                                                        float* __restrict__ agg) {
    int gid  = blockIdx.x * 256 + threadIdx.x;
    int row  = gid >> 6;
    int lane = threadIdx.x & 63;
    if (row >= N_NODES) return;
    int s = row_start[row];
    int e = row_start[row + 1];
    float4 acc = make_float4(0.f, 0.f, 0.f, 0.f);
    for (int i = s; i < e; ++i) {
        int   c = scol[i];
        float v = sval[i];
        float4 a = ((const float4*)(x + (size_t)c * D))[lane];
        acc.x += v * a.x;
        acc.y += v * a.y;
        acc.z += v * a.z;
        acc.w += v * a.w;
    }
    ((float4*)(agg + (size_t)row * D))[lane] = acc;
}

// --- GEMM + bias + relu: 128x128 tile, 8x8 per-thread micro-tile ---------
#define GBM 128
#define GBN 128
#define GBK 16
#define LDA (GBM + 4)   // +4 floats: keeps 16B alignment for b128 reads
#define LDB (GBN + 4)

__global__ __launch_bounds__(256) void gemm_bias_relu(const float* __restrict__ A,
                                                      const float* __restrict__ W,
                                                      const float* __restrict__ bias,
                                                      float* __restrict__ out) {
    __shared__ float a_s[GBK][LDA];   // A transposed: a_s[k][m]
    __shared__ float b_s[GBK][LDB];   // B as-is:      b_s[k][n]

    int t    = threadIdx.x;
    int mblk = blockIdx.x >> 1;
    int nblk = blockIdx.x & 1;
    int m0   = mblk * GBM;
    int n0   = nblk * GBN;

    int tm = t & 15;     // micro-tile row group
    int tn = t >> 4;     // micro-tile col group

    // cooperative-load mappings
    int am = t >> 1;           // 0..127 (A row within tile)
    int ak = (t & 1) * 8;      // 0 or 8 (A k-offset)
    int bk = t >> 4;           // 0..15  (B k within tile)
    int bn = (t & 15) * 8;     // B col offset

    float acc[8][8];
#pragma unroll
    for (int i = 0; i < 8; ++i)
#pragma unroll
        for (int j = 0; j < 8; ++j) acc[i][j] = 0.f;

    for (int k0 = 0; k0 < D; k0 += GBK) {
        int gm = m0 + am;
        float4 av0, av1;
        if (gm < N_NODES) {
            const float* ap = A + (size_t)gm * D + k0 + ak;
            av0 = ((const float4*)ap)[0];
            av1 = ((const float4*)ap)[1];
        } else {
            av0 = make_float4(0.f, 0.f, 0.f, 0.f);
            av1 = av0;
        }
        a_s[ak + 0][am] = av0.x;
        a_s[ak + 1][am] = av0.y;
        a_s[ak + 2][am] = av0.z;
        a_s[ak + 3][am] = av0.w;
        a_s[ak + 4][am] = av1.x;
        a_s[ak + 5][am] = av1.y;
        a_s[ak + 6][am] = av1.z;
        a_s[ak + 7][am] = av1.w;

        const float* wp = W + (size_t)(k0 + bk) * D + n0 + bn;
        float4 bv0 = ((const float4*)wp)[0];
        float4 bv1 = ((const float4*)wp)[1];
        *((float4*)&b_s[bk][bn])     = bv0;
        *((float4*)&b_s[bk][bn + 4]) = bv1;

        __syncthreads();

#pragma unroll
        for (int kk = 0; kk < GBK; ++kk) {
            float4 a0 = *((const float4*)&a_s[kk][tm * 8]);
            float4 a1 = *((const float4*)&a_s[kk][tm * 8 + 4]);
            float4 b0 = *((const float4*)&b_s[kk][tn * 8]);
            float4 b1 = *((const float4*)&b_s[kk][tn * 8 + 4]);
            float af[8] = {a0.x, a0.y, a0.z, a0.w, a1.x, a1.y, a1.z, a1.w};
            float bf[8] = {b0.x, b0.y, b0.z, b0.w, b1.x, b1.y, b1.z, b1.w};
#pragma unroll
            for (int i = 0; i < 8; ++i)
#pragma unroll
                for (int j = 0; j < 8; ++j)
                    acc[i][j] += af[i] * bf[j];
        }
        __syncthreads();
    }

    float bv[8];
#pragma unroll
    for (int j = 0; j < 8; ++j) bv[j] = bias[n0 + tn * 8 + j];

#pragma unroll
    for (int i = 0; i < 8; ++i) {
        int m = m0 + tm * 8 + i;
        if (m < N_NODES) {
            float o[8];
#pragma unroll
            for (int j = 0; j < 8; ++j) {
                float v = acc[i][j] + bv[j];
                o[j] = v > 0.f ? v : 0.f;
            }
            float4* op = (float4*)(out + (size_t)m * D + n0 + tn * 8);
            op[0] = make_float4(o[0], o[1], o[2], o[3]);
            op[1] = make_float4(o[4], o[5], o[6], o[7]);
        }
    }
}

extern "C" void kernel_launch(void* const* d_in, const int* in_sizes, int n_in,
                              void* d_out, int out_size, void* d_ws, size_t ws_size,
                              hipStream_t stream) {
    const float* x     = (const float*)d_in[0];
    const int*   erow  = (const int*)d_in[1];
    const int*   ecol  = (const int*)d_in[2];
    const float* evals = (const float*)d_in[3];
    const float* W     = (const float*)d_in[4];
    const float* bias  = (const float*)d_in[5];
    float*       out   = (float*)d_out;

    // workspace carve-up
    char* ws = (char*)d_ws;
    float* agg       = (float*)ws;                 ws += (size_t)N_NODES * D * sizeof(float);
    int*   cnt       = (int*)ws;                   ws += (size_t)N_NODES * sizeof(int);
    int*   row_start = (int*)ws;                   ws += (size_t)(N_NODES + 1) * sizeof(int);
    int*   cursor    = (int*)ws;                   ws += (size_t)N_NODES * sizeof(int);
    ws = (char*)(((uintptr_t)ws + 15) & ~(uintptr_t)15);
    int*   scol      = (int*)ws;                   ws += (size_t)N_EDGES * sizeof(int);
    float* sval      = (float*)ws;

    hipMemsetAsync(cnt, 0, (size_t)N_NODES * sizeof(int), stream);

    int eblocks = (N_EDGES + 255) / 256;                       // 3125
    hist_kernel<<<eblocks, 256, 0, stream>>>(erow, cnt);
    scan_kernel<<<1, 1024, 0, stream>>>(cnt, row_start, cursor);
    scatter_kernel<<<eblocks, 256, 0, stream>>>(erow, ecol, evals, cursor, scol, sval);

    int ablocks = (N_NODES * 64 + 255) / 256;                  // 12500
    aggregate_kernel<<<ablocks, 256, 0, stream>>>(x, row_start, scol, sval, agg);

    int gblocks = ((N_NODES + GBM - 1) / GBM) * (D / GBN);     // 391 * 2 = 782
    gemm_bias_relu<<<gblocks, 256, 0, stream>>>(agg, W, bias, out);
}

// Round 3
// 392.133 us; speedup vs baseline: 9.0011x; 1.3073x over previous
//
#include <hip/hip_runtime.h>

#define N_NODES 50000
#define N_EDGES 800000
#define D 256

#define SCHUNK 256
#define NPART ((N_NODES + SCHUNK - 1) / SCHUNK)   // 196

// ---------------------------------------------------------------------------
// Workspace layout:
//   agg  : N_NODES*D floats (51.2 MB)
//   cnt  : N_NODES ints
//   row_start : N_NODES+1 ints
//   cursor    : N_NODES ints
//   part      : NPART ints
//   spay      : N_EDGES int2 (col, val bits)
// ---------------------------------------------------------------------------

// --- CSR step 1: histogram of row degrees --------------------------------
__global__ __launch_bounds__(256) void hist_kernel(const int* __restrict__ erow,
                                                   int* __restrict__ cnt) {
    int e = blockIdx.x * 256 + threadIdx.x;
    if (e < N_EDGES) atomicAdd(&cnt[erow[e]], 1);
}

// --- CSR step 2a: per-chunk partial sums ---------------------------------
__global__ __launch_bounds__(256) void partial_sum_kernel(const int* __restrict__ cnt,
                                                          int* __restrict__ part) {
    __shared__ int s[256];
    int idx = blockIdx.x * SCHUNK + threadIdx.x;
    int v = (idx < N_NODES) ? cnt[idx] : 0;
    s[threadIdx.x] = v;
    __syncthreads();
    for (int off = 128; off > 0; off >>= 1) {
        if (threadIdx.x < off) s[threadIdx.x] += s[threadIdx.x + off];
        __syncthreads();
    }
    if (threadIdx.x == 0) part[blockIdx.x] = s[0];
}

// --- CSR step 2b: scan the 196 partials (single tiny block) --------------
__global__ __launch_bounds__(256) void scan_part_kernel(int* __restrict__ part) {
    __shared__ int s[256];
    int t = threadIdx.x;
    int v = (t < NPART) ? part[t] : 0;
    s[t] = v;
    __syncthreads();
    for (int off = 1; off < 256; off <<= 1) {
        int u = (t >= off) ? s[t - off] : 0;
        __syncthreads();
        s[t] += u;
        __syncthreads();
    }
    if (t < NPART) part[t] = s[t] - v;   // exclusive
}

// --- CSR step 2c: per-chunk exclusive scan + global offset ---------------
__global__ __launch_bounds__(256) void scan_final_kernel(const int* __restrict__ cnt,
                                                         const int* __restrict__ part,
                                                         int* __restrict__ row_start,
                                                         int* __restrict__ cursor) {
    __shared__ int s[256];
    int b = blockIdx.x;
    int t = threadIdx.x;
    int idx = b * SCHUNK + t;
    int v = (idx < N_NODES) ? cnt[idx] : 0;
    s[t] = v;
    __syncthreads();
    for (int off = 1; off < 256; off <<= 1) {
        int u = (t >= off) ? s[t - off] : 0;
        __syncthreads();
        s[t] += u;
        __syncthreads();
    }
    if (idx < N_NODES) {
        int excl = s[t] - v + part[b];
        row_start[idx] = excl;
        cursor[idx]    = excl;
    }
    if (b == 0 && t == 0) row_start[N_NODES] = N_EDGES;
}

// --- CSR step 3: scatter edge payloads into row-sorted order -------------
__global__ __launch_bounds__(256) void scatter_kernel(const int* __restrict__ erow,
                                                      const int* __restrict__ ecol,
                                                      const float* __restrict__ evals,
                                                      int* __restrict__ cursor,
                                                      int2* __restrict__ spay) {
    int e = blockIdx.x * 256 + threadIdx.x;
    if (e >= N_EDGES) return;
    int r = erow[e];
    int pos = atomicAdd(&cursor[r], 1);
    spay[pos] = make_int2(ecol[e], __float_as_int(evals[e]));
}

// --- Aggregation: one wave per row, no atomics ---------------------------
__global__ __launch_bounds__(256) void aggregate_kernel(const float* __restrict__ x,
                                                        const int* __restrict__ row_start,
                                                        const int2* __restrict__ spay,
                                                        float* __restrict__ agg) {
    int gid  = blockIdx.x * 256 + threadIdx.x;
    int row  = gid >> 6;
    int lane = threadIdx.x & 63;
    if (row >= N_NODES) return;
    int s = row_start[row];
    int e = row_start[row + 1];
    float4 acc = make_float4(0.f, 0.f, 0.f, 0.f);
    for (int i = s; i < e; ++i) {
        int2  p = spay[i];
        int   c = p.x;
        float v = __int_as_float(p.y);
        float4 a = ((const float4*)(x + (size_t)c * D))[lane];
        acc.x += v * a.x;
        acc.y += v * a.y;
        acc.z += v * a.z;
        acc.w += v * a.w;
    }
    ((float4*)(agg + (size_t)row * D))[lane] = acc;
}

// --- GEMM + bias + relu: 128x128 tile, 8x8 per-thread micro-tile ---------
#define GBM 128
#define GBN 128
#define GBK 16
#define LDA (GBM + 4)
#define LDB (GBN + 4)

__global__ __launch_bounds__(256) void gemm_bias_relu(const float* __restrict__ A,
                                                      const float* __restrict__ W,
                                                      const float* __restrict__ bias,
                                                      float* __restrict__ out) {
    __shared__ float a_s[GBK][LDA];
    __shared__ float b_s[GBK][LDB];

    int t    = threadIdx.x;
    int mblk = blockIdx.x >> 1;
    int nblk = blockIdx.x & 1;
    int m0   = mblk * GBM;
    int n0   = nblk * GBN;

    int tm = t & 15;
    int tn = t >> 4;

    int am = t >> 1;
    int ak = (t & 1) * 8;
    int bk = t >> 4;
    int bn = (t & 15) * 8;

    float acc[8][8];
#pragma unroll
    for (int i = 0; i < 8; ++i)
#pragma unroll
        for (int j = 0; j < 8; ++j) acc[i][j] = 0.f;

    for (int k0 = 0; k0 < D; k0 += GBK) {
        int gm = m0 + am;
        float4 av0, av1;
        if (gm < N_NODES) {
            const float* ap = A + (size_t)gm * D + k0 + ak;
            av0 = ((const float4*)ap)[0];
            av1 = ((const float4*)ap)[1];
        } else {
            av0 = make_float4(0.f, 0.f, 0.f, 0.f);
            av1 = av0;
        }
        a_s[ak + 0][am] = av0.x;
        a_s[ak + 1][am] = av0.y;
        a_s[ak + 2][am] = av0.z;
        a_s[ak + 3][am] = av0.w;
        a_s[ak + 4][am] = av1.x;
        a_s[ak + 5][am] = av1.y;
        a_s[ak + 6][am] = av1.z;
        a_s[ak + 7][am] = av1.w;

        const float* wp = W + (size_t)(k0 + bk) * D + n0 + bn;
        float4 bv0 = ((const float4*)wp)[0];
        float4 bv1 = ((const float4*)wp)[1];
        *((float4*)&b_s[bk][bn])     = bv0;
        *((float4*)&b_s[bk][bn + 4]) = bv1;

        __syncthreads();

#pragma unroll
        for (int kk = 0; kk < GBK; ++kk) {
            float4 a0 = *((const float4*)&a_s[kk][tm * 8]);
            float4 a1 = *((const float4*)&a_s[kk][tm * 8 + 4]);
            float4 b0 = *((const float4*)&b_s[kk][tn * 8]);
            float4 b1 = *((const float4*)&b_s[kk][tn * 8 + 4]);
            float af[8] = {a0.x, a0.y, a0.z, a0.w, a1.x, a1.y, a1.z, a1.w};
            float bf[8] = {b0.x, b0.y, b0.z, b0.w, b1.x, b1.y, b1.z, b1.w};
#pragma unroll
            for (int i = 0; i < 8; ++i)
#pragma unroll
                for (int j = 0; j < 8; ++j)
                    acc[i][j] += af[i] * bf[j];
        }
        __syncthreads();
    }

    float bv[8];
#pragma unroll
    for (int j = 0; j < 8; ++j) bv[j] = bias[n0 + tn * 8 + j];

#pragma unroll
    for (int i = 0; i < 8; ++i) {
        int m = m0 + tm * 8 + i;
        if (m < N_NODES) {
            float o[8];
#pragma unroll
            for (int j = 0; j < 8; ++j) {
                float v = acc[i][j] + bv[j];
                o[j] = v > 0.f ? v : 0.f;
            }
            float4* op = (float4*)(out + (size_t)m * D + n0 + tn * 8);
            op[0] = make_float4(o[0], o[1], o[2], o[3]);
            op[1] = make_float4(o[4], o[5], o[6], o[7]);
        }
    }
}

extern "C" void kernel_launch(void* const* d_in, const int* in_sizes, int n_in,
                              void* d_out, int out_size, void* d_ws, size_t ws_size,
                              hipStream_t stream) {
    const float* x     = (const float*)d_in[0];
    const int*   erow  = (const int*)d_in[1];
    const int*   ecol  = (const int*)d_in[2];
    const float* evals = (const float*)d_in[3];
    const float* W     = (const float*)d_in[4];
    const float* bias  = (const float*)d_in[5];
    float*       out   = (float*)d_out;

    char* ws = (char*)d_ws;
    float* agg       = (float*)ws;   ws += (size_t)N_NODES * D * sizeof(float);
    int*   cnt       = (int*)ws;     ws += (size_t)N_NODES * sizeof(int);
    int*   row_start = (int*)ws;     ws += (size_t)(N_NODES + 1) * sizeof(int);
    int*   cursor    = (int*)ws;     ws += (size_t)N_NODES * sizeof(int);
    int*   part      = (int*)ws;     ws += (size_t)NPART * sizeof(int);
    ws = (char*)(((uintptr_t)ws + 15) & ~(uintptr_t)15);
    int2*  spay      = (int2*)ws;

    hipMemsetAsync(cnt, 0, (size_t)N_NODES * sizeof(int), stream);

    int eblocks = (N_EDGES + 255) / 256;   // 3125
    hist_kernel<<<eblocks, 256, 0, stream>>>(erow, cnt);
    partial_sum_kernel<<<NPART, 256, 0, stream>>>(cnt, part);
    scan_part_kernel<<<1, 256, 0, stream>>>(part);
    scan_final_kernel<<<NPART, 256, 0, stream>>>(cnt, part, row_start, cursor);
    scatter_kernel<<<eblocks, 256, 0, stream>>>(erow, ecol, evals, cursor, spay);

    int ablocks = (N_NODES * 64 + 255) / 256;   // 12500
    aggregate_kernel<<<ablocks, 256, 0, stream>>>(x, row_start, spay, agg);

    int gblocks = ((N_NODES + GBM - 1) / GBM) * (D / GBN);   // 782
    gemm_bias_relu<<<gblocks, 256, 0, stream>>>(agg, W, bias, out);
}

// Round 4
// 309.268 us; speedup vs baseline: 11.4128x; 1.2679x over previous
//
#include <hip/hip_runtime.h>

#define N_NODES 50000
#define N_EDGES 800000
#define D 256

#define SCHUNK 256
#define NPART ((N_NODES + SCHUNK - 1) / SCHUNK)   // 196

typedef __attribute__((ext_vector_type(8))) short short8;
typedef __attribute__((ext_vector_type(4))) float f32x4;

typedef const __attribute__((address_space(1))) unsigned int* as1_u32p;
typedef __attribute__((address_space(3))) unsigned int* as3_u32p;

__device__ __forceinline__ unsigned short f2bf(float f) {
    unsigned int u = __float_as_uint(f);
    u = (u + 0x7fffu + ((u >> 16) & 1u)) >> 16;   // RTNE
    return (unsigned short)u;
}

// --- convert x: fp32 -> bf16, 1 float4 per thread ------------------------
__global__ __launch_bounds__(256) void convert_x(const float4* __restrict__ x,
                                                 ushort4* __restrict__ xh) {
    int i = blockIdx.x * 256 + threadIdx.x;           // over N_NODES*D/4
    float4 v = x[i];
    xh[i] = make_ushort4(f2bf(v.x), f2bf(v.y), f2bf(v.z), f2bf(v.w));
}

// --- convert + transpose W: Wt[n][k] = bf16(W[k][n]) ---------------------
__global__ __launch_bounds__(256) void convert_w(const float* __restrict__ W,
                                                 unsigned short* __restrict__ Wt) {
    int idx = blockIdx.x * 256 + threadIdx.x;         // 65536
    int k = idx >> 8, n = idx & 255;
    Wt[n * 256 + k] = f2bf(W[idx]);
}

// --- CSR step 1: histogram -----------------------------------------------
__global__ __launch_bounds__(256) void hist_kernel(const int* __restrict__ erow,
                                                   int* __restrict__ cnt) {
    int e = blockIdx.x * 256 + threadIdx.x;
    if (e < N_EDGES) atomicAdd(&cnt[erow[e]], 1);
}

// --- CSR step 2a: per-chunk partial sums ---------------------------------
__global__ __launch_bounds__(256) void partial_sum_kernel(const int* __restrict__ cnt,
                                                          int* __restrict__ part) {
    __shared__ int s[256];
    int idx = blockIdx.x * SCHUNK + threadIdx.x;
    int v = (idx < N_NODES) ? cnt[idx] : 0;
    s[threadIdx.x] = v;
    __syncthreads();
    for (int off = 128; off > 0; off >>= 1) {
        if (threadIdx.x < off) s[threadIdx.x] += s[threadIdx.x + off];
        __syncthreads();
    }
    if (threadIdx.x == 0) part[blockIdx.x] = s[0];
}

// --- CSR step 2b: scan partials (single tiny block) ----------------------
__global__ __launch_bounds__(256) void scan_part_kernel(int* __restrict__ part) {
    __shared__ int s[256];
    int t = threadIdx.x;
    int v = (t < NPART) ? part[t] : 0;
    s[t] = v;
    __syncthreads();
    for (int off = 1; off < 256; off <<= 1) {
        int u = (t >= off) ? s[t - off] : 0;
        __syncthreads();
        s[t] += u;
        __syncthreads();
    }
    if (t < NPART) part[t] = s[t] - v;
}

// --- CSR step 2c: final scan + offsets -----------------------------------
__global__ __launch_bounds__(256) void scan_final_kernel(const int* __restrict__ cnt,
                                                         const int* __restrict__ part,
                                                         int* __restrict__ row_start,
                                                         int* __restrict__ cursor) {
    __shared__ int s[256];
    int b = blockIdx.x, t = threadIdx.x;
    int idx = b * SCHUNK + t;
    int v = (idx < N_NODES) ? cnt[idx] : 0;
    s[t] = v;
    __syncthreads();
    for (int off = 1; off < 256; off <<= 1) {
        int u = (t >= off) ? s[t - off] : 0;
        __syncthreads();
        s[t] += u;
        __syncthreads();
    }
    if (idx < N_NODES) {
        int excl = s[t] - v + part[b];
        row_start[idx] = excl;
        cursor[idx]    = excl;
    }
    if (b == 0 && t == 0) row_start[N_NODES] = N_EDGES;
}

// --- CSR step 3: scatter payloads ----------------------------------------
__global__ __launch_bounds__(256) void scatter_kernel(const int* __restrict__ erow,
                                                      const int* __restrict__ ecol,
                                                      const float* __restrict__ evals,
                                                      int* __restrict__ cursor,
                                                      int2* __restrict__ spay) {
    int e = blockIdx.x * 256 + threadIdx.x;
    if (e >= N_EDGES) return;
    int r = erow[e];
    int pos = atomicAdd(&cursor[r], 1);
    spay[pos] = make_int2(ecol[e], __float_as_int(evals[e]));
}

// --- Aggregation: wave per row, bf16 gather, fp32 accumulate, bf16 store -
__global__ __launch_bounds__(256) void aggregate_kernel(const unsigned short* __restrict__ xh,
                                                        const int* __restrict__ row_start,
                                                        const int2* __restrict__ spay,
                                                        unsigned short* __restrict__ aggh) {
    int gid  = blockIdx.x * 256 + threadIdx.x;
    int row  = gid >> 6;
    int lane = threadIdx.x & 63;
    if (row >= N_NODES) return;
    int s = row_start[row];
    int e = row_start[row + 1];
    float a0 = 0.f, a1 = 0.f, a2 = 0.f, a3 = 0.f;
    for (int i = s; i < e; ++i) {
        int2  p = spay[i];
        float v = __int_as_float(p.y);
        uint2 q = ((const uint2*)(xh + (size_t)p.x * D))[lane];
        a0 += v * __uint_as_float(q.x << 16);
        a1 += v * __uint_as_float(q.x & 0xffff0000u);
        a2 += v * __uint_as_float(q.y << 16);
        a3 += v * __uint_as_float(q.y & 0xffff0000u);
    }
    ushort4 o = make_ushort4(f2bf(a0), f2bf(a1), f2bf(a2), f2bf(a3));
    ((ushort4*)(aggh + (size_t)row * D))[lane] = o;
}

// --- GEMM: bf16 MFMA, 128x128 tile, BK=32, fused bias+relu ---------------
// A = aggh [M=50000, K=256] row-major bf16, B = Wt [N=256, K=256] row-major
// bf16 (W transposed). out[m][n] = relu(sum_k A[m][k]*Wt[n][k] + bias[n]).
__global__ __launch_bounds__(256) void gemm_mfma(const unsigned short* __restrict__ A,
                                                 const unsigned short* __restrict__ Wt,
                                                 const float* __restrict__ bias,
                                                 float* __restrict__ out) {
    __shared__ unsigned short As[128 * 32];   // row-major, 64B rows
    __shared__ unsigned short Bs[128 * 32];

    int t    = threadIdx.x;
    int w    = t >> 6;          // wave 0..3
    int lane = t & 63;
    int wm   = w & 1;           // wave grid 2x2, each wave 64x64
    int wn   = w >> 1;
    int mblk = blockIdx.x >> 1;
    int nblk = blockIdx.x & 1;
    int m0   = mblk * 128;
    int n0   = nblk * 128;

    f32x4 acc[4][4];
#pragma unroll
    for (int i = 0; i < 4; ++i)
#pragma unroll
        for (int j = 0; j < 4; ++j) acc[i][j] = (f32x4){0.f, 0.f, 0.f, 0.f};

    int lq = lane >> 2;         // 0..15: row within 16-row group
    int lr = lane & 3;          // 0..3 : 16B chunk within 64B row

    for (int k0 = 0; k0 < D; k0 += 32) {
        // stage A tile: wave w covers rows w*16+{0..15} and 64+w*16+{0..15}
#pragma unroll
        for (int i = 0; i < 2; ++i) {
            int r0 = i * 64 + w * 16;
            int gm = m0 + r0 + lq;
            if (gm > N_NODES - 1) gm = N_NODES - 1;
            const unsigned short* gp = A + (size_t)gm * D + k0 + lr * 8;
            __builtin_amdgcn_global_load_lds((as1_u32p)gp, (as3_u32p)(As + r0 * 32), 16, 0, 0);
        }
        // stage B tile (Wt rows n0..n0+127)
#pragma unroll
        for (int i = 0; i < 2; ++i) {
            int r0 = i * 64 + w * 16;
            int gn = n0 + r0 + lq;
            const unsigned short* gp = Wt + (size_t)gn * D + k0 + lr * 8;
            __builtin_amdgcn_global_load_lds((as1_u32p)gp, (as3_u32p)(Bs + r0 * 32), 16, 0, 0);
        }
        __syncthreads();

        short8 af[4], bf[4];
        int kq = (lane >> 4) * 8;     // k-chunk for this lane
        int lm = lane & 15;
#pragma unroll
        for (int mt = 0; mt < 4; ++mt)
            af[mt] = *(const short8*)(As + (wm * 64 + mt * 16 + lm) * 32 + kq);
#pragma unroll
        for (int nt = 0; nt < 4; ++nt)
            bf[nt] = *(const short8*)(Bs + (wn * 64 + nt * 16 + lm) * 32 + kq);
#pragma unroll
        for (int mt = 0; mt < 4; ++mt)
#pragma unroll
            for (int nt = 0; nt < 4; ++nt)
                acc[mt][nt] = __builtin_amdgcn_mfma_f32_16x16x32_bf16(af[mt], bf[nt], acc[mt][nt], 0, 0, 0);
        __syncthreads();
    }

    // epilogue: C[row=(lane>>4)*4+r][col=lane&15] per frag
    int cl = lane & 15;
    int cr = (lane >> 4) * 4;
#pragma unroll
    for (int nt = 0; nt < 4; ++nt) {
        int n = n0 + wn * 64 + nt * 16 + cl;
        float b = bias[n];
#pragma unroll
        for (int mt = 0; mt < 4; ++mt) {
            int mbase = m0 + wm * 64 + mt * 16 + cr;
#pragma unroll
            for (int r = 0; r < 4; ++r) {
                int m = mbase + r;
                if (m < N_NODES) {
                    float v = acc[mt][nt][r] + b;
                    out[(size_t)m * D + n] = v > 0.f ? v : 0.f;
                }
            }
        }
    }
}

extern "C" void kernel_launch(void* const* d_in, const int* in_sizes, int n_in,
                              void* d_out, int out_size, void* d_ws, size_t ws_size,
                              hipStream_t stream) {
    const float* x     = (const float*)d_in[0];
    const int*   erow  = (const int*)d_in[1];
    const int*   ecol  = (const int*)d_in[2];
    const float* evals = (const float*)d_in[3];
    const float* W     = (const float*)d_in[4];
    const float* bias  = (const float*)d_in[5];
    float*       out   = (float*)d_out;

    char* ws = (char*)d_ws;
    unsigned short* xh   = (unsigned short*)ws;  ws += (size_t)N_NODES * D * 2;   // 25.6 MB
    unsigned short* aggh = (unsigned short*)ws;  ws += (size_t)N_NODES * D * 2;   // 25.6 MB
    unsigned short* Wt   = (unsigned short*)ws;  ws += (size_t)D * D * 2;         // 128 KB
    int* cnt       = (int*)ws;  ws += (size_t)N_NODES * sizeof(int);
    int* row_start = (int*)ws;  ws += (size_t)(N_NODES + 1) * sizeof(int);
    int* cursor    = (int*)ws;  ws += (size_t)N_NODES * sizeof(int);
    int* part      = (int*)ws;  ws += (size_t)NPART * sizeof(int);
    ws = (char*)(((uintptr_t)ws + 15) & ~(uintptr_t)15);
    int2* spay     = (int2*)ws;                                                   // 6.4 MB

    hipMemsetAsync(cnt, 0, (size_t)N_NODES * sizeof(int), stream);

    convert_x<<<(N_NODES * D / 4 + 255) / 256, 256, 0, stream>>>((const float4*)x, (ushort4*)xh);
    convert_w<<<(D * D + 255) / 256, 256, 0, stream>>>(W, Wt);

    int eblocks = (N_EDGES + 255) / 256;
    hist_kernel<<<eblocks, 256, 0, stream>>>(erow, cnt);
    partial_sum_kernel<<<NPART, 256, 0, stream>>>(cnt, part);
    scan_part_kernel<<<1, 256, 0, stream>>>(part);
    scan_final_kernel<<<NPART, 256, 0, stream>>>(cnt, part, row_start, cursor);
    scatter_kernel<<<eblocks, 256, 0, stream>>>(erow, ecol, evals, cursor, spay);

    int ablocks = (N_NODES * 64 + 255) / 256;   // 12500
    aggregate_kernel<<<ablocks, 256, 0, stream>>>(xh, row_start, spay, aggh);

    int gblocks = ((N_NODES + 127) / 128) * 2;  // 391*2 = 782
    gemm_mfma<<<gblocks, 256, 0, stream>>>(aggh, Wt, bias, out);
}

// Round 5
// 281.877 us; speedup vs baseline: 12.5218x; 1.0972x over previous
//
#include <hip/hip_runtime.h>

#define N_NODES 50000
#define N_EDGES 800000
#define D 256

#define SCHUNK 256
#define NPART ((N_NODES + SCHUNK - 1) / SCHUNK)   // 196

typedef __attribute__((ext_vector_type(8))) short short8;
typedef __attribute__((ext_vector_type(4))) float f32x4;

typedef const __attribute__((address_space(1))) unsigned int* as1_u32p;
typedef __attribute__((address_space(3))) unsigned int* as3_u32p;

__device__ __forceinline__ unsigned short f2bf(float f) {
    unsigned int u = __float_as_uint(f);
    u = (u + 0x7fffu + ((u >> 16) & 1u)) >> 16;   // RTNE
    return (unsigned short)u;
}

// --- convert x: fp32 -> bf16, 1 float4 per thread ------------------------
__global__ __launch_bounds__(256) void convert_x(const float4* __restrict__ x,
                                                 ushort4* __restrict__ xh) {
    int i = blockIdx.x * 256 + threadIdx.x;           // over N_NODES*D/4
    float4 v = x[i];
    xh[i] = make_ushort4(f2bf(v.x), f2bf(v.y), f2bf(v.z), f2bf(v.w));
}

// --- convert + transpose W: Wt[n][k] = bf16(W[k][n]) ---------------------
__global__ __launch_bounds__(256) void convert_w(const float* __restrict__ W,
                                                 unsigned short* __restrict__ Wt) {
    int idx = blockIdx.x * 256 + threadIdx.x;         // 65536
    int k = idx >> 8, n = idx & 255;
    Wt[n * 256 + k] = f2bf(W[idx]);
}

// --- CSR step 1: histogram -----------------------------------------------
__global__ __launch_bounds__(256) void hist_kernel(const int* __restrict__ erow,
                                                   int* __restrict__ cnt) {
    int e = blockIdx.x * 256 + threadIdx.x;
    if (e < N_EDGES) atomicAdd(&cnt[erow[e]], 1);
}

// --- CSR step 2a: per-chunk partial sums ---------------------------------
__global__ __launch_bounds__(256) void partial_sum_kernel(const int* __restrict__ cnt,
                                                          int* __restrict__ part) {
    __shared__ int s[256];
    int idx = blockIdx.x * SCHUNK + threadIdx.x;
    int v = (idx < N_NODES) ? cnt[idx] : 0;
    s[threadIdx.x] = v;
    __syncthreads();
    for (int off = 128; off > 0; off >>= 1) {
        if (threadIdx.x < off) s[threadIdx.x] += s[threadIdx.x + off];
        __syncthreads();
    }
    if (threadIdx.x == 0) part[blockIdx.x] = s[0];
}

// --- CSR step 2b: scan partials (single tiny block) ----------------------
__global__ __launch_bounds__(256) void scan_part_kernel(int* __restrict__ part) {
    __shared__ int s[256];
    int t = threadIdx.x;
    int v = (t < NPART) ? part[t] : 0;
    s[t] = v;
    __syncthreads();
    for (int off = 1; off < 256; off <<= 1) {
        int u = (t >= off) ? s[t - off] : 0;
        __syncthreads();
        s[t] += u;
        __syncthreads();
    }
    if (t < NPART) part[t] = s[t] - v;
}

// --- CSR step 2c: final scan + offsets -----------------------------------
__global__ __launch_bounds__(256) void scan_final_kernel(const int* __restrict__ cnt,
                                                         const int* __restrict__ part,
                                                         int* __restrict__ row_start,
                                                         int* __restrict__ cursor) {
    __shared__ int s[256];
    int b = blockIdx.x, t = threadIdx.x;
    int idx = b * SCHUNK + t;
    int v = (idx < N_NODES) ? cnt[idx] : 0;
    s[t] = v;
    __syncthreads();
    for (int off = 1; off < 256; off <<= 1) {
        int u = (t >= off) ? s[t - off] : 0;
        __syncthreads();
        s[t] += u;
        __syncthreads();
    }
    if (idx < N_NODES) {
        int excl = s[t] - v + part[b];
        row_start[idx] = excl;
        cursor[idx]    = excl;
    }
    if (b == 0 && t == 0) row_start[N_NODES] = N_EDGES;
}

// --- CSR step 3: scatter payloads ----------------------------------------
__global__ __launch_bounds__(256) void scatter_kernel(const int* __restrict__ erow,
                                                      const int* __restrict__ ecol,
                                                      const float* __restrict__ evals,
                                                      int* __restrict__ cursor,
                                                      int2* __restrict__ spay) {
    int e = blockIdx.x * 256 + threadIdx.x;
    if (e >= N_EDGES) return;
    int r = erow[e];
    int pos = atomicAdd(&cursor[r], 1);
    spay[pos] = make_int2(ecol[e], __float_as_int(evals[e]));
}

// --- Aggregation: wave per row, unroll x4 for memory-level parallelism ---
// bf16 gather, fp32 accumulate, bf16 store. Payload loads are consecutive
// (one cache line, wave-broadcast); the 4 gathers are independent so 4
// vmem requests stay in flight per wave instead of 1.
__global__ __launch_bounds__(256) void aggregate_kernel(const unsigned short* __restrict__ xh,
                                                        const int* __restrict__ row_start,
                                                        const int2* __restrict__ spay,
                                                        unsigned short* __restrict__ aggh) {
    int gid  = blockIdx.x * 256 + threadIdx.x;
    int row  = gid >> 6;
    int lane = threadIdx.x & 63;
    if (row >= N_NODES) return;
    int s = row_start[row];
    int e = row_start[row + 1];
    float a0 = 0.f, a1 = 0.f, a2 = 0.f, a3 = 0.f;
    int i = s;
    for (; i + 4 <= e; i += 4) {
        int2 p0 = spay[i + 0];
        int2 p1 = spay[i + 1];
        int2 p2 = spay[i + 2];
        int2 p3 = spay[i + 3];
        uint2 q0 = ((const uint2*)(xh + (size_t)p0.x * D))[lane];
        uint2 q1 = ((const uint2*)(xh + (size_t)p1.x * D))[lane];
        uint2 q2 = ((const uint2*)(xh + (size_t)p2.x * D))[lane];
        uint2 q3 = ((const uint2*)(xh + (size_t)p3.x * D))[lane];
        float v0 = __int_as_float(p0.y);
        float v1 = __int_as_float(p1.y);
        float v2 = __int_as_float(p2.y);
        float v3 = __int_as_float(p3.y);
        a0 += v0 * __uint_as_float(q0.x << 16);
        a1 += v0 * __uint_as_float(q0.x & 0xffff0000u);
        a2 += v0 * __uint_as_float(q0.y << 16);
        a3 += v0 * __uint_as_float(q0.y & 0xffff0000u);
        a0 += v1 * __uint_as_float(q1.x << 16);
        a1 += v1 * __uint_as_float(q1.x & 0xffff0000u);
        a2 += v1 * __uint_as_float(q1.y << 16);
        a3 += v1 * __uint_as_float(q1.y & 0xffff0000u);
        a0 += v2 * __uint_as_float(q2.x << 16);
        a1 += v2 * __uint_as_float(q2.x & 0xffff0000u);
        a2 += v2 * __uint_as_float(q2.y << 16);
        a3 += v2 * __uint_as_float(q2.y & 0xffff0000u);
        a0 += v3 * __uint_as_float(q3.x << 16);
        a1 += v3 * __uint_as_float(q3.x & 0xffff0000u);
        a2 += v3 * __uint_as_float(q3.y << 16);
        a3 += v3 * __uint_as_float(q3.y & 0xffff0000u);
    }
    for (; i < e; ++i) {
        int2  p = spay[i];
        float v = __int_as_float(p.y);
        uint2 q = ((const uint2*)(xh + (size_t)p.x * D))[lane];
        a0 += v * __uint_as_float(q.x << 16);
        a1 += v * __uint_as_float(q.x & 0xffff0000u);
        a2 += v * __uint_as_float(q.y << 16);
        a3 += v * __uint_as_float(q.y & 0xffff0000u);
    }
    ushort4 o = make_ushort4(f2bf(a0), f2bf(a1), f2bf(a2), f2bf(a3));
    ((ushort4*)(aggh + (size_t)row * D))[lane] = o;
}

// --- GEMM: bf16 MFMA, 128x128 tile, BK=32, fused bias+relu ---------------
__global__ __launch_bounds__(256) void gemm_mfma(const unsigned short* __restrict__ A,
                                                 const unsigned short* __restrict__ Wt,
                                                 const float* __restrict__ bias,
                                                 float* __restrict__ out) {
    __shared__ unsigned short As[128 * 32];
    __shared__ unsigned short Bs[128 * 32];

    int t    = threadIdx.x;
    int w    = t >> 6;
    int lane = t & 63;
    int wm   = w & 1;
    int wn   = w >> 1;
    int mblk = blockIdx.x >> 1;
    int nblk = blockIdx.x & 1;
    int m0   = mblk * 128;
    int n0   = nblk * 128;

    f32x4 acc[4][4];
#pragma unroll
    for (int i = 0; i < 4; ++i)
#pragma unroll
        for (int j = 0; j < 4; ++j) acc[i][j] = (f32x4){0.f, 0.f, 0.f, 0.f};

    int lq = lane >> 2;
    int lr = lane & 3;

    for (int k0 = 0; k0 < D; k0 += 32) {
#pragma unroll
        for (int i = 0; i < 2; ++i) {
            int r0 = i * 64 + w * 16;
            int gm = m0 + r0 + lq;
            if (gm > N_NODES - 1) gm = N_NODES - 1;
            const unsigned short* gp = A + (size_t)gm * D + k0 + lr * 8;
            __builtin_amdgcn_global_load_lds((as1_u32p)gp, (as3_u32p)(As + r0 * 32), 16, 0, 0);
        }
#pragma unroll
        for (int i = 0; i < 2; ++i) {
            int r0 = i * 64 + w * 16;
            int gn = n0 + r0 + lq;
            const unsigned short* gp = Wt + (size_t)gn * D + k0 + lr * 8;
            __builtin_amdgcn_global_load_lds((as1_u32p)gp, (as3_u32p)(Bs + r0 * 32), 16, 0, 0);
        }
        __syncthreads();

        short8 af[4], bf[4];
        int kq = (lane >> 4) * 8;
        int lm = lane & 15;
#pragma unroll
        for (int mt = 0; mt < 4; ++mt)
            af[mt] = *(const short8*)(As + (wm * 64 + mt * 16 + lm) * 32 + kq);
#pragma unroll
        for (int nt = 0; nt < 4; ++nt)
            bf[nt] = *(const short8*)(Bs + (wn * 64 + nt * 16 + lm) * 32 + kq);
#pragma unroll
        for (int mt = 0; mt < 4; ++mt)
#pragma unroll
            for (int nt = 0; nt < 4; ++nt)
                acc[mt][nt] = __builtin_amdgcn_mfma_f32_16x16x32_bf16(af[mt], bf[nt], acc[mt][nt], 0, 0, 0);
        __syncthreads();
    }

    int cl = lane & 15;
    int cr = (lane >> 4) * 4;
#pragma unroll
    for (int nt = 0; nt < 4; ++nt) {
        int n = n0 + wn * 64 + nt * 16 + cl;
        float b = bias[n];
#pragma unroll
        for (int mt = 0; mt < 4; ++mt) {
            int mbase = m0 + wm * 64 + mt * 16 + cr;
#pragma unroll
            for (int r = 0; r < 4; ++r) {
                int m = mbase + r;
                if (m < N_NODES) {
                    float v = acc[mt][nt][r] + b;
                    out[(size_t)m * D + n] = v > 0.f ? v : 0.f;
                }
            }
        }
    }
}

extern "C" void kernel_launch(void* const* d_in, const int* in_sizes, int n_in,
                              void* d_out, int out_size, void* d_ws, size_t ws_size,
                              hipStream_t stream) {
    const float* x     = (const float*)d_in[0];
    const int*   erow  = (const int*)d_in[1];
    const int*   ecol  = (const int*)d_in[2];
    const float* evals = (const float*)d_in[3];
    const float* W     = (const float*)d_in[4];
    const float* bias  = (const float*)d_in[5];
    float*       out   = (float*)d_out;

    char* ws = (char*)d_ws;
    unsigned short* xh   = (unsigned short*)ws;  ws += (size_t)N_NODES * D * 2;
    unsigned short* aggh = (unsigned short*)ws;  ws += (size_t)N_NODES * D * 2;
    unsigned short* Wt   = (unsigned short*)ws;  ws += (size_t)D * D * 2;
    int* cnt       = (int*)ws;  ws += (size_t)N_NODES * sizeof(int);
    int* row_start = (int*)ws;  ws += (size_t)(N_NODES + 1) * sizeof(int);
    int* cursor    = (int*)ws;  ws += (size_t)N_NODES * sizeof(int);
    int* part      = (int*)ws;  ws += (size_t)NPART * sizeof(int);
    ws = (char*)(((uintptr_t)ws + 15) & ~(uintptr_t)15);
    int2* spay     = (int2*)ws;

    hipMemsetAsync(cnt, 0, (size_t)N_NODES * sizeof(int), stream);

    convert_x<<<(N_NODES * D / 4 + 255) / 256, 256, 0, stream>>>((const float4*)x, (ushort4*)xh);
    convert_w<<<(D * D + 255) / 256, 256, 0, stream>>>(W, Wt);

    int eblocks = (N_EDGES + 255) / 256;
    hist_kernel<<<eblocks, 256, 0, stream>>>(erow, cnt);
    partial_sum_kernel<<<NPART, 256, 0, stream>>>(cnt, part);
    scan_part_kernel<<<1, 256, 0, stream>>>(part);
    scan_final_kernel<<<NPART, 256, 0, stream>>>(cnt, part, row_start, cursor);
    scatter_kernel<<<eblocks, 256, 0, stream>>>(erow, ecol, evals, cursor, spay);

    int ablocks = (N_NODES * 64 + 255) / 256;   // 12500
    aggregate_kernel<<<ablocks, 256, 0, stream>>>(xh, row_start, spay, aggh);

    int gblocks = ((N_NODES + 127) / 128) * 2;  // 782
    gemm_mfma<<<gblocks, 256, 0, stream>>>(aggh, Wt, bias, out);
}